// Round 10
// baseline (146.475 us; speedup 1.0000x reference)
//
#include <hip/hip_runtime.h>
#include <hip/hip_bf16.h>
#include <cstdint>
#include <cstddef>

#define T_DIM 2048
#define C_DIM 1024
#define NH 16
#define HS 64
#define KSP 64

// QKV GEMM: 128x128 tile, BK=64 (m97 geometry), XOR-swizzled LDS,
// global_load_lds staging. 32 B staged per output element (was 48).
#define QBM 128
#define QBN 128
#define QBK 64
// o-proj GEMM: 64x64 tile (512 blocks = 2/CU) — R6 config
#define OBM 64
#define OBN 64
#define GBK 128

// attention tiling (R9-verified): ATB=16 t's per block, 2 heads (1/wave).
#define ATB 16
#define VTS 102   // Vt row stride (shorts): odd u32-stride 51 -> ~2-way
#define PLS 96    // Pl row stride (shorts): 192B, 16B-aligned b128 reads

typedef short short8 __attribute__((ext_vector_type(8)));
typedef float f32x4 __attribute__((ext_vector_type(4)));
typedef _Float16 half8 __attribute__((ext_vector_type(8)));

__device__ __forceinline__ unsigned short f2bfu(float f) {
  unsigned u = __builtin_bit_cast(unsigned, f);
  unsigned r = (u + 0x7fffu + ((u >> 16) & 1u)) >> 16;
  return (unsigned short)r;
}
__device__ __forceinline__ unsigned short f2h(float f) {
  _Float16 h = (_Float16)f;
  return __builtin_bit_cast(unsigned short, h);
}

#define GLOAD_LDS16(gp, lp)                                                  \
  __builtin_amdgcn_global_load_lds(                                          \
      (const __attribute__((address_space(1))) void*)(gp),                   \
      (__attribute__((address_space(3))) void*)(lp), 16, 0, 0)

// ---- launch 1: key_scores (blocks [0,512)) + f32->bf16 conversion (rest) ----
#define NSCORE (T_DIM / 4)  // 512
#define NCONV ((T_DIM * C_DIM + 4 * C_DIM * C_DIM) / 4 / 256)  // 6144
__global__ __launch_bounds__(256) void convert_scores_kernel(
    const float* __restrict__ x, const float* __restrict__ Wq,
    const float* __restrict__ Wk, const float* __restrict__ Wv,
    const float* __restrict__ Wo, const float* __restrict__ Wks,
    const float* __restrict__ bks,
    unsigned short* __restrict__ xb, unsigned short* __restrict__ Wqb,
    unsigned short* __restrict__ Wkb, unsigned short* __restrict__ Wvb,
    unsigned short* __restrict__ Wob, float* __restrict__ scores) {
  if (blockIdx.x < NSCORE) {
    const int t = blockIdx.x * 4 + (threadIdx.x >> 6);
    const int lane = threadIdx.x & 63;
    const float* xrow = x + (size_t)t * C_DIM;
    float acc = 0.f;
    #pragma unroll 4
    for (int i = lane; i < C_DIM; i += 64)
      acc += xrow[i] * Wks[i];
    #pragma unroll
    for (int o = 32; o; o >>= 1) acc += __shfl_xor(acc, o);
    if (lane == 0) scores[t] = acc + bks[0];
    return;
  }
  const int i = (blockIdx.x - NSCORE) * 256 + threadIdx.x;
  const int NX4 = T_DIM * C_DIM / 4;
  const int NW4 = C_DIM * C_DIM / 4;
  const float* src;
  unsigned short* dst;
  int j = i;
  if (j < NX4) { src = x; dst = xb; }
  else {
    j -= NX4;
    int w = j / NW4;
    j -= w * NW4;
    src = (w == 0) ? Wq : (w == 1) ? Wk : (w == 2) ? Wv : Wo;
    dst = (w == 0) ? Wqb : (w == 1) ? Wkb : (w == 2) ? Wvb : Wob;
  }
  float4 f = reinterpret_cast<const float4*>(src)[j];
  ushort4 o;
  o.x = f2bfu(f.x); o.y = f2bfu(f.y); o.z = f2bfu(f.z); o.w = f2bfu(f.w);
  reinterpret_cast<ushort4*>(dst)[j] = o;
}

// ---- QKV GEMM body: 128x128 tile, BK=64 (m97 geometry); LDS 32 KB ----
// Staging: wave w, iter i stages 8 rows (i*32+w*8 .. +7) x 64 shorts; LDS
// dest is wave-uniform (lane lands at +lane*16B = row(lane>>3), chunk
// (lane&7)); global source pre-swizzled by chunk ^ (row&7). Read side:
// pc = ((ks*4+quad) ^ (r&7))*8 — identical algebra to the verified 128x64
// body (BK=64 row = 8 chunks = the XOR-8 swizzle domain).
__device__ __forceinline__ void gemm_body_128x128(
    const unsigned short* __restrict__ A, const unsigned short* __restrict__ W,
    f32x4 acc[4][4], int bm, int bn, int tid,
    unsigned short* As, unsigned short* Ws) {
  const int w = tid >> 6, lane = tid & 63;
  const int quad = lane >> 4, r = lane & 15;
  const int wm = (w >> 1) * 64, wn = (w & 1) * 64;
  const int sub8 = lane >> 3;  // 0..7
  const int c8 = lane & 7;     // 0..7
  const unsigned short* Arow[4];
  const unsigned short* Wrow[4];
  #pragma unroll
  for (int i = 0; i < 4; ++i) {
    const int row = i * 32 + w * 8 + sub8;
    Arow[i] = A + (size_t)(bm * QBM + row) * C_DIM + ((c8 ^ (row & 7)) * 8);
    Wrow[i] = W + (size_t)(bn * QBN + row) * C_DIM + ((c8 ^ (row & 7)) * 8);
  }
  for (int kb = 0; kb < C_DIM; kb += QBK) {
    #pragma unroll
    for (int i = 0; i < 4; ++i)
      GLOAD_LDS16(Arow[i] + kb, &As[(i * 32 + w * 8) * QBK]);
    #pragma unroll
    for (int i = 0; i < 4; ++i)
      GLOAD_LDS16(Wrow[i] + kb, &Ws[(i * 32 + w * 8) * QBK]);
    __syncthreads();
    #pragma unroll
    for (int ks = 0; ks < 2; ++ks) {
      const int pc = ((ks * 4 + quad) ^ (r & 7)) * 8;
      short8 af[4], bfr[4];
      #pragma unroll
      for (int mi = 0; mi < 4; ++mi)
        af[mi] = *reinterpret_cast<const short8*>(&As[(wm + mi * 16 + r) * QBK + pc]);
      #pragma unroll
      for (int ni = 0; ni < 4; ++ni)
        bfr[ni] = *reinterpret_cast<const short8*>(&Ws[(wn + ni * 16 + r) * QBK + pc]);
      #pragma unroll
      for (int mi = 0; mi < 4; ++mi)
        #pragma unroll
        for (int ni = 0; ni < 4; ++ni)
          acc[mi][ni] = __builtin_amdgcn_mfma_f32_16x16x32_bf16(af[mi], bfr[ni], acc[mi][ni], 0, 0, 0);
    }
    __syncthreads();
  }
}

// ---- launch 2: rank_sort (blocks [0,512)) + fused QKV GEMM (rest). ----
#define NRANK (T_DIM / 4)  // 512
#define QPER ((T_DIM / QBM) * (C_DIM / QBN))  // 128
__global__ __launch_bounds__(256) void gemm_qkv_rank_kernel(
    const unsigned short* __restrict__ A,
    const unsigned short* __restrict__ Wq, const unsigned short* __restrict__ Wk,
    const unsigned short* __restrict__ Wv,
    const float* __restrict__ bq, const float* __restrict__ bk,
    const float* __restrict__ bv,
    unsigned short* __restrict__ qo, unsigned short* __restrict__ ko,
    unsigned short* __restrict__ vo,
    const float* __restrict__ scores, int* __restrict__ sorted_idx) {
  __shared__ unsigned short lds[2 * QBM * QBK];  // 32 KB arena
  const int tid = threadIdx.x;
  if (blockIdx.x < NRANK) {
    // rank-by-counting sort: one wave per element, lane-parallel scan
    float* ss = reinterpret_cast<float*>(lds);  // first 8 KB of arena
    for (int j = tid; j < T_DIM; j += 256) ss[j] = scores[j];
    __syncthreads();
    const int w = tid >> 6, lane = tid & 63;
    const int i = blockIdx.x * 4 + w;
    const float si = ss[i];
    int rank = 0;
    #pragma unroll
    for (int step = 0; step < T_DIM / 64; ++step) {
      const int j = step * 64 + lane;
      const float sj = ss[j];
      rank += (int)((sj > si) || (sj == si && j < i));
    }
    #pragma unroll
    for (int o = 32; o; o >>= 1) rank += __shfl_xor(rank, o);
    if (lane == 0) sorted_idx[rank] = i;
    return;
  }
  const int bid = blockIdx.x - NRANK;
  const int which = bid / QPER;
  const int rem = bid % QPER;
  const int bm = rem / (C_DIM / QBN);
  const int bn = rem % (C_DIM / QBN);
  const unsigned short* W = (which == 0) ? Wq : (which == 1) ? Wk : Wv;
  const float* bias = (which == 0) ? bq : (which == 1) ? bk : bv;
  unsigned short* out = (which == 0) ? qo : (which == 1) ? ko : vo;
  f32x4 acc[4][4] = {};
  gemm_body_128x128(A, W, acc, bm, bn, tid, lds, lds + QBM * QBK);
  const int w = tid >> 6, lane = tid & 63;
  const int quad = lane >> 4, r = lane & 15;
  const int wm = (w >> 1) * 64, wn = (w & 1) * 64;
  #pragma unroll
  for (int mi = 0; mi < 4; ++mi) {
    #pragma unroll
    for (int ni = 0; ni < 4; ++ni) {
      const int col = bn * QBN + wn + ni * 16 + r;
      const float bf = bias[col];
      #pragma unroll
      for (int i = 0; i < 4; ++i) {
        const int row = bm * QBM + wm + mi * 16 + quad * 4 + i;
        const float val = acc[mi][ni][i] + bf;
        // q,k,v all f16 (MFMA f16 path in attn; f16 V >= bf16 precision)
        out[(size_t)row * C_DIM + col] = f2h(val);
      }
    }
  }
}

// ---- o-proj GEMM body: 64x64 tile, BK=128 (R6-verified) ----
__device__ __forceinline__ void gemm_body_64x64(
    const unsigned short* __restrict__ A, const unsigned short* __restrict__ W,
    f32x4 acc[2][2], int bm, int bn, int tid) {
  __shared__ unsigned short As[OBM * GBK];  // 16 KB
  __shared__ unsigned short Ws[OBN * GBK];  // 16 KB
  const int w = tid >> 6, lane = tid & 63;
  const int quad = lane >> 4, r = lane & 15;
  const int wm = (w >> 1) * 32, wn = (w & 1) * 32;
  const int sub = lane >> 4;
  const int c = lane & 15;
  const unsigned short* Arow[4];
  const unsigned short* Wrow[4];
  #pragma unroll
  for (int i = 0; i < 4; ++i) {
    const int row = w * 16 + i * 4 + sub;
    Arow[i] = A + (size_t)(bm * OBM + row) * C_DIM + ((c ^ (row & 7)) * 8);
    Wrow[i] = W + (size_t)(bn * OBN + row) * C_DIM + ((c ^ (row & 7)) * 8);
  }
  for (int kb = 0; kb < C_DIM; kb += GBK) {
    #pragma unroll
    for (int i = 0; i < 4; ++i)
      GLOAD_LDS16(Arow[i] + kb, &As[(w * 16 + i * 4) * GBK]);
    #pragma unroll
    for (int i = 0; i < 4; ++i)
      GLOAD_LDS16(Wrow[i] + kb, &Ws[(w * 16 + i * 4) * GBK]);
    __syncthreads();
    #pragma unroll
    for (int ks = 0; ks < 4; ++ks) {
      const int pc = ((ks * 4 + quad) ^ (r & 7)) * 8;
      short8 af[2], bfr[2];
      #pragma unroll
      for (int mi = 0; mi < 2; ++mi)
        af[mi] = *reinterpret_cast<const short8*>(&As[(wm + mi * 16 + r) * GBK + pc]);
      #pragma unroll
      for (int ni = 0; ni < 2; ++ni)
        bfr[ni] = *reinterpret_cast<const short8*>(&Ws[(wn + ni * 16 + r) * GBK + pc]);
      #pragma unroll
      for (int mi = 0; mi < 2; ++mi)
        #pragma unroll
        for (int ni = 0; ni < 2; ++ni)
          acc[mi][ni] = __builtin_amdgcn_mfma_f32_16x16x32_bf16(af[mi], bfr[ni], acc[mi][ni], 0, 0, 0);
    }
    __syncthreads();
  }
}

// ---- launch 5: output projection GEMM, fp32 out, 64x64 tile ----
__global__ __launch_bounds__(256) void gemm_o_f32_kernel(
    const unsigned short* __restrict__ A, const unsigned short* __restrict__ W,
    const float* __restrict__ bias, float* __restrict__ out) {
  const int tid = threadIdx.x;
  const int bm = blockIdx.x / (C_DIM / OBN);
  const int bn = blockIdx.x % (C_DIM / OBN);
  f32x4 acc[2][2] = {};
  gemm_body_64x64(A, W, acc, bm, bn, tid);
  const int w = tid >> 6, lane = tid & 63;
  const int quad = lane >> 4, r = lane & 15;
  const int wm = (w >> 1) * 32, wn = (w & 1) * 32;
  #pragma unroll
  for (int mi = 0; mi < 2; ++mi) {
    #pragma unroll
    for (int ni = 0; ni < 2; ++ni) {
      const int col = bn * OBN + wn + ni * 16 + r;
      const float bf = bias[col];
      #pragma unroll
      for (int i = 0; i < 4; ++i) {
        const int row = bm * OBM + wm + mi * 16 + quad * 4 + i;
        out[(size_t)row * C_DIM + col] = acc[mi][ni][i] + bf;
      }
    }
  }
}

// ---- launch 3: per-t top-64 selection (one wave per t, u16 row indices) ----
__global__ __launch_bounds__(256) void select_kernel(
    const int* __restrict__ sorted_idx, unsigned short* __restrict__ sel) {
  const int tid = threadIdx.x;
  const int w = tid >> 6, lane = tid & 63;
  const int t = blockIdx.x * 4 + w;
  unsigned short* dst = sel + (size_t)t * KSP;
  if (t <= 63) {
    // reference semantics: rows 0..t-1 once, row t duplicated (clamped -inf picks)
    dst[lane] = (unsigned short)((lane < t) ? lane : t);
    return;
  }
  const unsigned long long lt_mask = (1ull << lane) - 1ull;
  int count = 0;
  for (int c = 0; c < T_DIM / 64 && count < KSP; ++c) {
    int s = sorted_idx[c * 64 + lane];
    s = (s < 0) ? 0 : (s > T_DIM - 1 ? T_DIM - 1 : s);
    const bool ok = (s <= t);
    const unsigned long long mm = __ballot(ok);
    const int pos = count + __popcll(mm & lt_mask);
    if (ok && pos < KSP) dst[pos] = (unsigned short)s;
    count += __popcll(mm);
  }
}

// ---- launch 4: MFMA sparse attention, K direct-to-register (R9-verified).
// 32.4 KB arena -> 5 blocks/CU x 2 waves. ----
__global__ __launch_bounds__(128) void attn_kernel(
    const unsigned short* __restrict__ q, const unsigned short* __restrict__ k,
    const unsigned short* __restrict__ v, const unsigned short* __restrict__ sel,
    unsigned short* __restrict__ attn_out) {
  // arena carve:
  //   [0,26112)      Vt: 2 x 64 x 102 shorts
  //   [26112,32256)  Pl: 2 x 16 x 96 shorts; overlay map8[2048]+cnt8[1280]
  //   [32256,32416)  urows[80]
  __shared__ __align__(16) unsigned char arena[32416];
  unsigned short* VtB = reinterpret_cast<unsigned short*>(arena);
  unsigned short* PlB = reinterpret_cast<unsigned short*>(arena + 26112);
  unsigned char* map8 = arena + 26112;
  unsigned char* cnt8 = arena + 26112 + 2048;
  unsigned short* urows = reinterpret_cast<unsigned short*>(arena + 32256);
  const int tb = blockIdx.x >> 3;
  const int hg = blockIdx.x & 7;
  const int t0 = tb * ATB;
  const int tid = threadIdx.x;
  const int w = tid >> 6, lane = tid & 63;
  const int qd = lane >> 4;      // quad
  const int r = lane & 15;
  const int h = hg * 2 + w;
  unsigned short* Vtw = VtB + w * 64 * VTS;
  unsigned short* Plw = PlB + w * 16 * PLS;

  // hoist Q B-frags (global f16): lane (qd,r) holds Q[t0+r][kc*32+qd*8 ..+7]
  uint4 qf[2];
  #pragma unroll
  for (int kc = 0; kc < 2; ++kc)
    qf[kc] = *reinterpret_cast<const uint4*>(
        q + (size_t)(t0 + r) * C_DIM + h * HS + kc * 32 + qd * 8);

  // phase A: positional union (slots 0..78 + pad 79), map build (t0>=64),
  // cnt zero-init (t0>=64 path only; analytic path overwrites all entries)
  if (tid < KSP) {
    const int r0 = sel[(size_t)t0 * KSP + tid];
    urows[tid] = (unsigned short)r0;
    if (t0 >= 64) map8[r0] = (unsigned char)tid;  // rows distinct -> no race
  } else if (tid < 79) {
    const int row = t0 + 1 + (tid - KSP);
    urows[tid] = (unsigned short)row;
    if (t0 >= 64) map8[row] = (unsigned char)tid;
  } else if (tid == 79) {
    urows[79] = (unsigned short)t0;   // pad slot: real data, cnt=0 -> masked
  }
  if (t0 >= 64) {
    for (int i = tid; i < 320; i += 128)
      reinterpret_cast<unsigned*>(cnt8)[i] = 0u;
  }
  __syncthreads();

  // K A-frags direct from global: lane (qd,r) holds K[urows[ut*16+r]][kc*32+qd*8..+7]
  uint4 kf[5][2];
  #pragma unroll
  for (int ut = 0; ut < 5; ++ut) {
    const int rowg = urows[ut * 16 + r];
    const unsigned short* kr = k + (size_t)rowg * C_DIM + h * HS + qd * 8;
    kf[ut][0] = *reinterpret_cast<const uint4*>(kr);
    kf[ut][1] = *reinterpret_cast<const uint4*>(kr + 32);
  }

  // phase B: per-wave V gather/transpose + cooperative cnt build
  {
    const int e8 = lane & 7;
    const int pr = lane >> 3;  // row-pair id 0..7
    #pragma unroll
    for (int sb = 0; sb < 5; ++sb) {
      const int s0 = sb * 16 + pr * 2;
      const int row0 = urows[s0], row1 = urows[s0 + 1];
      const size_t g0 = (size_t)row0 * C_DIM + h * HS + e8 * 8;
      const size_t g1 = (size_t)row1 * C_DIM + h * HS + e8 * 8;
      const uint4 v0 = *reinterpret_cast<const uint4*>(v + g0);
      const uint4 v1 = *reinterpret_cast<const uint4*>(v + g1);
      const unsigned* v0w = reinterpret_cast<const unsigned*>(&v0);
      const unsigned* v1w = reinterpret_cast<const unsigned*>(&v1);
      // transpose-scatter: Vt[d][s0..s0+1] as one u32 (pair-packed)
      #pragma unroll
      for (int dd = 0; dd < 8; ++dd) {
        const unsigned lo = (v0w[dd >> 1] >> ((dd & 1) * 16)) & 0xffffu;
        const unsigned hi = (v1w[dd >> 1] >> ((dd & 1) * 16)) & 0xffffu;
        *reinterpret_cast<unsigned*>(&Vtw[(e8 * 8 + dd) * VTS + s0]) =
            lo | (hi << 16);
      }
    }
    // zero Vt pad cols u=80..95
    #pragma unroll
    for (int z = 0; z < 8; ++z)
      *reinterpret_cast<unsigned*>(&Vtw[lane * VTS + 80 + z * 2]) = 0u;
    // cnt build (shared by both waves, cooperative)
    if (t0 >= 64) {
      #pragma unroll
      for (int e = 0; e < 8; ++e) {
        const int idx = tid + e * 128;
        const int tl = idx >> 6;
        const int rr = sel[(size_t)(t0 + tl) * KSP + (idx & 63)];
        cnt8[tl * 80 + map8[rr]] = 1;  // distinct rows per t -> no race
      }
    } else if (tid < 80) {
      // analytic multiplicities for t<64: sel(t) = rows 0..t-1 once +
      // row t x(64-t). Deterministic dup slot = t0.
      const int s = tid;
      #pragma unroll
      for (int tl = 0; tl < ATB; ++tl) {
        const int t = t0 + tl;
        int c;
        if (s < t0)        c = 1;
        else if (s == t0)  c = (tl == 0) ? (64 - t) : 1;
        else if (s < 64)   c = 0;                     // unused dup slots
        else if (s < 79) {
          const int row = t0 + 1 + (s - 64);
          c = (row < t) ? 1 : ((row == t) ? (64 - t) : 0);
        } else c = 0;                                 // pad slot
        cnt8[tl * 80 + s] = (unsigned char)c;
      }
    }
  }
  __syncthreads();

  // S^T = K @ Q^T; lane holds S[u=ut*16+qd*4+i][t=r]
  f32x4 s5[5] = {};
  #pragma unroll
  for (int ut = 0; ut < 5; ++ut) {
    #pragma unroll
    for (int kc = 0; kc < 2; ++kc) {
      s5[ut] = __builtin_amdgcn_mfma_f32_16x16x32_f16(
          __builtin_bit_cast(half8, kf[ut][kc]), __builtin_bit_cast(half8, qf[kc]),
          s5[ut], 0, 0, 0);
    }
  }
  // bias (mask/multiplicity) + row-max
  float mx = -3.0e38f;
  #pragma unroll
  for (int ut = 0; ut < 5; ++ut) {
    const unsigned c4 =
        *reinterpret_cast<const unsigned*>(cnt8 + r * 80 + ut * 16 + qd * 4);
    #pragma unroll
    for (int i = 0; i < 4; ++i) {
      const unsigned cc = (c4 >> (8 * i)) & 0xffu;
      float lg = s5[ut][i] * 0.125f;
      lg = (cc == 0u) ? -3.0e38f
         : (cc == 1u) ? lg : (lg + __logf((float)cc));
      s5[ut][i] = lg;
      mx = fmaxf(mx, lg);
    }
  }
  mx = fmaxf(mx, __shfl_xor(mx, 16));
  mx = fmaxf(mx, __shfl_xor(mx, 32));
  float sum = 0.f;
  #pragma unroll
  for (int ut = 0; ut < 5; ++ut)
    #pragma unroll
    for (int i = 0; i < 4; ++i) {
      const float e = __expf(s5[ut][i] - mx);
      s5[ut][i] = e;
      sum += e;
    }
  sum += __shfl_xor(sum, 16);
  sum += __shfl_xor(sum, 32);
  const float rs = 1.0f / sum;
  // barrier: cnt8/map8 (overlaid on Pl) must be fully read by BOTH waves
  // before any Pl write
  __syncthreads();
  // P -> f16 into Pl[t][u] (wave-local roundtrip)
  #pragma unroll
  for (int ut = 0; ut < 5; ++ut) {
    const unsigned w0 = (unsigned)f2h(s5[ut][0] * rs) |
                        ((unsigned)f2h(s5[ut][1] * rs) << 16);
    const unsigned w1 = (unsigned)f2h(s5[ut][2] * rs) |
                        ((unsigned)f2h(s5[ut][3] * rs) << 16);
    unsigned* p32 = reinterpret_cast<unsigned*>(&Plw[r * PLS + ut * 16 + qd * 4]);
    p32[0] = w0;
    p32[1] = w1;
  }
  // zero Pl pad u=80..95 (4 shorts per quad)
  *reinterpret_cast<unsigned long long*>(&Plw[r * PLS + 80 + qd * 4]) = 0ull;
  // PV: O^T[d][t] = Vt @ P; A = Vt rows (d), B = Pl cols (t)
  f32x4 o4[4] = {};
  #pragma unroll
  for (int c = 0; c < 3; ++c) {
    const uint4 pw = *reinterpret_cast<const uint4*>(&Plw[r * PLS + c * 32 + qd * 8]);
    #pragma unroll
    for (int mt = 0; mt < 4; ++mt) {
      const unsigned short* vb_ = &Vtw[(mt * 16 + r) * VTS + c * 32 + qd * 8];
      uint4 vw;
      vw.x = *reinterpret_cast<const unsigned*>(vb_);
      vw.y = *reinterpret_cast<const unsigned*>(vb_ + 2);
      vw.z = *reinterpret_cast<const unsigned*>(vb_ + 4);
      vw.w = *reinterpret_cast<const unsigned*>(vb_ + 6);
      o4[mt] = __builtin_amdgcn_mfma_f32_16x16x32_f16(
          __builtin_bit_cast(half8, vw), __builtin_bit_cast(half8, pw),
          o4[mt], 0, 0, 0);
    }
  }
  // store: lane holds O[t=r][d = mt*16 + qd*4 + i], bf16 out
  #pragma unroll
  for (int mt = 0; mt < 4; ++mt) {
    ushort4 ov;
    ov.x = f2bfu(o4[mt][0]); ov.y = f2bfu(o4[mt][1]);
    ov.z = f2bfu(o4[mt][2]); ov.w = f2bfu(o4[mt][3]);
    *reinterpret_cast<ushort4*>(
        attn_out + (size_t)(t0 + r) * C_DIM + h * HS + mt * 16 + qd * 4) = ov;
  }
}

extern "C" void kernel_launch(void* const* d_in, const int* in_sizes, int n_in,
                              void* d_out, int out_size, void* d_ws, size_t ws_size,
                              hipStream_t stream) {
  const float* x   = (const float*)d_in[0];
  const float* Wq  = (const float*)d_in[1];
  const float* bq  = (const float*)d_in[2];
  const float* Wk  = (const float*)d_in[3];
  const float* bk  = (const float*)d_in[4];
  const float* Wv  = (const float*)d_in[5];
  const float* bv  = (const float*)d_in[6];
  const float* Wo  = (const float*)d_in[7];
  const float* bo  = (const float*)d_in[8];
  const float* Wks = (const float*)d_in[9];
  const float* bks = (const float*)d_in[10];
  float* out = (float*)d_out;

  char* ws = (char*)d_ws;
  size_t off = 0;
  float* scores = (float*)(ws + off); off += 8192;
  int*   sorted = (int*)(ws + off);   off += 8192;
  unsigned short* selb = (unsigned short*)(ws + off); off += (size_t)T_DIM * KSP * 2;
  unsigned short* xb  = (unsigned short*)(ws + off); off += (size_t)T_DIM * C_DIM * 2;
  unsigned short* Wqb = (unsigned short*)(ws + off); off += (size_t)C_DIM * C_DIM * 2;
  unsigned short* Wkb = (unsigned short*)(ws + off); off += (size_t)C_DIM * C_DIM * 2;
  unsigned short* Wvb = (unsigned short*)(ws + off); off += (size_t)C_DIM * C_DIM * 2;
  unsigned short* Wob = (unsigned short*)(ws + off); off += (size_t)C_DIM * C_DIM * 2;
  unsigned short* qb  = (unsigned short*)(ws + off); off += (size_t)T_DIM * C_DIM * 2;
  unsigned short* kb  = (unsigned short*)(ws + off); off += (size_t)T_DIM * C_DIM * 2;
  unsigned short* vb  = (unsigned short*)(ws + off); off += (size_t)T_DIM * C_DIM * 2;
  unsigned short* ab  = xb;  // alias: xb dead after gemm_qkv

  // launch 1: conversion + scores
  convert_scores_kernel<<<NSCORE + NCONV, 256, 0, stream>>>(
      x, Wq, Wk, Wv, Wo, Wks, bks, xb, Wqb, Wkb, Wvb, Wob, scores);

  // launch 2: rank-sort (512 blocks) + fused QKV GEMM (384 blocks, 128x128)
  gemm_qkv_rank_kernel<<<NRANK + 3 * QPER, 256, 0, stream>>>(
      xb, Wqb, Wkb, Wvb, bq, bk, bv, qb, kb, vb, scores, sorted);

  // launch 3: per-t top-64 selection (one wave per t)
  select_kernel<<<T_DIM / 4, 256, 0, stream>>>(sorted, selb);

  // launch 4: MFMA attention (128 t-tiles x 8 head-pairs = 1024 blocks)
  attn_kernel<<<(T_DIM / ATB) * (NH / 2), 128, 0, stream>>>(qb, kb, vb, selb, ab);

  // launch 5: output projection (512 blocks, 64x64)
  gemm_o_f32_kernel<<<(T_DIM / OBM) * (C_DIM / OBN), 256, 0, stream>>>(
      ab, Wob, bo, out);
}

// Round 11
// 142.516 us; speedup vs baseline: 1.0278x; 1.0278x over previous
//
#include <hip/hip_runtime.h>
#include <hip/hip_bf16.h>
#include <cstdint>
#include <cstddef>

#define T_DIM 2048
#define C_DIM 1024
#define NH 16
#define HS 64
#define KSP 64

// QKV fused GEMM: 128x32-per-weight tile, BK=64, A staged ONCE for q/k/v.
// 28 KB LDS -> 5 blocks/CU; af fragments reused across 3 weights.
#define FBM 128
#define FBN 32
#define FBK 64
#define FPER ((T_DIM / FBM) * (C_DIM / FBN))  // 512
// o-proj GEMM: 64x64 tile (512 blocks = 2/CU) — R6 config
#define OBM 64
#define OBN 64
#define GBK 128

// attention tiling (R9-verified): ATB=16 t's per block, 2 heads (1/wave).
#define ATB 16
#define VTS 102   // Vt row stride (shorts): odd u32-stride 51 -> ~2-way
#define PLS 96    // Pl row stride (shorts): 192B, 16B-aligned b128 reads

typedef short short8 __attribute__((ext_vector_type(8)));
typedef float f32x4 __attribute__((ext_vector_type(4)));
typedef _Float16 half8 __attribute__((ext_vector_type(8)));

__device__ __forceinline__ unsigned short f2bfu(float f) {
  unsigned u = __builtin_bit_cast(unsigned, f);
  unsigned r = (u + 0x7fffu + ((u >> 16) & 1u)) >> 16;
  return (unsigned short)r;
}
__device__ __forceinline__ unsigned short f2h(float f) {
  _Float16 h = (_Float16)f;
  return __builtin_bit_cast(unsigned short, h);
}

#define GLOAD_LDS16(gp, lp)                                                  \
  __builtin_amdgcn_global_load_lds(                                          \
      (const __attribute__((address_space(1))) void*)(gp),                   \
      (__attribute__((address_space(3))) void*)(lp), 16, 0, 0)

// ---- launch 1: key_scores (blocks [0,512)) + f32->bf16 conversion (rest) ----
#define NSCORE (T_DIM / 4)  // 512
#define NCONV ((T_DIM * C_DIM + 4 * C_DIM * C_DIM) / 4 / 256)  // 6144
__global__ __launch_bounds__(256) void convert_scores_kernel(
    const float* __restrict__ x, const float* __restrict__ Wq,
    const float* __restrict__ Wk, const float* __restrict__ Wv,
    const float* __restrict__ Wo, const float* __restrict__ Wks,
    const float* __restrict__ bks,
    unsigned short* __restrict__ xb, unsigned short* __restrict__ Wqb,
    unsigned short* __restrict__ Wkb, unsigned short* __restrict__ Wvb,
    unsigned short* __restrict__ Wob, float* __restrict__ scores) {
  if (blockIdx.x < NSCORE) {
    const int t = blockIdx.x * 4 + (threadIdx.x >> 6);
    const int lane = threadIdx.x & 63;
    const float* xrow = x + (size_t)t * C_DIM;
    float acc = 0.f;
    #pragma unroll 4
    for (int i = lane; i < C_DIM; i += 64)
      acc += xrow[i] * Wks[i];
    #pragma unroll
    for (int o = 32; o; o >>= 1) acc += __shfl_xor(acc, o);
    if (lane == 0) scores[t] = acc + bks[0];
    return;
  }
  const int i = (blockIdx.x - NSCORE) * 256 + threadIdx.x;
  const int NX4 = T_DIM * C_DIM / 4;
  const int NW4 = C_DIM * C_DIM / 4;
  const float* src;
  unsigned short* dst;
  int j = i;
  if (j < NX4) { src = x; dst = xb; }
  else {
    j -= NX4;
    int w = j / NW4;
    j -= w * NW4;
    src = (w == 0) ? Wq : (w == 1) ? Wk : (w == 2) ? Wv : Wo;
    dst = (w == 0) ? Wqb : (w == 1) ? Wkb : (w == 2) ? Wvb : Wob;
  }
  float4 f = reinterpret_cast<const float4*>(src)[j];
  ushort4 o;
  o.x = f2bfu(f.x); o.y = f2bfu(f.y); o.z = f2bfu(f.z); o.w = f2bfu(f.w);
  reinterpret_cast<ushort4*>(dst)[j] = o;
}

// ---- launch 2: rank_sort (blocks [0,512)) + FUSED QKV GEMM (rest).
// One block computes q,k,v for the same (bm,bn): A tile staged once per
// K-step, af fragments read once and reused across the 3 weights. ----
#define NRANK (T_DIM / 4)  // 512
__global__ __launch_bounds__(256) void gemm_qkv_rank_kernel(
    const unsigned short* __restrict__ A,
    const unsigned short* __restrict__ Wq, const unsigned short* __restrict__ Wk,
    const unsigned short* __restrict__ Wv,
    const float* __restrict__ bq, const float* __restrict__ bk,
    const float* __restrict__ bv,
    unsigned short* __restrict__ qo, unsigned short* __restrict__ ko,
    unsigned short* __restrict__ vo,
    const float* __restrict__ scores, int* __restrict__ sorted_idx) {
  __shared__ unsigned short lds[FBM * FBK + 3 * FBN * FBK];  // 28 KB arena
  const int tid = threadIdx.x;
  if (blockIdx.x < NRANK) {
    // rank-by-counting sort: one wave per element, lane-parallel scan
    float* ss = reinterpret_cast<float*>(lds);  // first 8 KB of arena
    for (int j = tid; j < T_DIM; j += 256) ss[j] = scores[j];
    __syncthreads();
    const int w = tid >> 6, lane = tid & 63;
    const int i = blockIdx.x * 4 + w;
    const float si = ss[i];
    int rank = 0;
    #pragma unroll
    for (int step = 0; step < T_DIM / 64; ++step) {
      const int j = step * 64 + lane;
      const float sj = ss[j];
      rank += (int)((sj > si) || (sj == si && j < i));
    }
    #pragma unroll
    for (int o = 32; o; o >>= 1) rank += __shfl_xor(rank, o);
    if (lane == 0) sorted_idx[rank] = i;
    return;
  }
  const int bid = blockIdx.x - NRANK;
  const int bm = bid >> 5;        // /32  (16 row-tiles)
  const int bn = bid & 31;        // 32 col-tiles of 32
  const int w = tid >> 6, lane = tid & 63;
  const int quad = lane >> 4, r = lane & 15;
  const int sub8 = lane >> 3, c8 = lane & 7;
  unsigned short* As = lds;
  unsigned short* Ws0 = lds + FBM * FBK;
  unsigned short* Ws1 = Ws0 + FBN * FBK;
  unsigned short* Ws2 = Ws1 + FBN * FBK;
  // A staging rows (4 issues x 32 rows), pre-swizzled source chunk
  const unsigned short* Arow[4];
  #pragma unroll
  for (int i = 0; i < 4; ++i) {
    const int row = i * 32 + w * 8 + sub8;
    Arow[i] = A + (size_t)(bm * FBM + row) * C_DIM + ((c8 ^ (row & 7)) * 8);
  }
  // W staging: 32 rows, one issue per weight
  const int wrow = w * 8 + sub8;
  const size_t woff = (size_t)(bn * FBN + wrow) * C_DIM + ((c8 ^ (wrow & 7)) * 8);
  f32x4 acc[3][2][2] = {};
  for (int kb = 0; kb < C_DIM; kb += FBK) {
    #pragma unroll
    for (int i = 0; i < 4; ++i)
      GLOAD_LDS16(Arow[i] + kb, &As[(i * 32 + w * 8) * FBK]);
    GLOAD_LDS16(Wq + woff + kb, &Ws0[(w * 8) * FBK]);
    GLOAD_LDS16(Wk + woff + kb, &Ws1[(w * 8) * FBK]);
    GLOAD_LDS16(Wv + woff + kb, &Ws2[(w * 8) * FBK]);
    __syncthreads();
    #pragma unroll
    for (int ks = 0; ks < 2; ++ks) {
      const int pc = ((ks * 4 + quad) ^ (r & 7)) * 8;
      short8 af[2];
      #pragma unroll
      for (int mi = 0; mi < 2; ++mi)
        af[mi] = *reinterpret_cast<const short8*>(&As[(w * 32 + mi * 16 + r) * FBK + pc]);
      // weight 0 (q)
      {
        short8 bfr[2];
        #pragma unroll
        for (int ni = 0; ni < 2; ++ni)
          bfr[ni] = *reinterpret_cast<const short8*>(&Ws0[(ni * 16 + r) * FBK + pc]);
        #pragma unroll
        for (int mi = 0; mi < 2; ++mi)
          #pragma unroll
          for (int ni = 0; ni < 2; ++ni)
            acc[0][mi][ni] = __builtin_amdgcn_mfma_f32_16x16x32_bf16(af[mi], bfr[ni], acc[0][mi][ni], 0, 0, 0);
      }
      // weight 1 (k)
      {
        short8 bfr[2];
        #pragma unroll
        for (int ni = 0; ni < 2; ++ni)
          bfr[ni] = *reinterpret_cast<const short8*>(&Ws1[(ni * 16 + r) * FBK + pc]);
        #pragma unroll
        for (int mi = 0; mi < 2; ++mi)
          #pragma unroll
          for (int ni = 0; ni < 2; ++ni)
            acc[1][mi][ni] = __builtin_amdgcn_mfma_f32_16x16x32_bf16(af[mi], bfr[ni], acc[1][mi][ni], 0, 0, 0);
      }
      // weight 2 (v)
      {
        short8 bfr[2];
        #pragma unroll
        for (int ni = 0; ni < 2; ++ni)
          bfr[ni] = *reinterpret_cast<const short8*>(&Ws2[(ni * 16 + r) * FBK + pc]);
        #pragma unroll
        for (int mi = 0; mi < 2; ++mi)
          #pragma unroll
          for (int ni = 0; ni < 2; ++ni)
            acc[2][mi][ni] = __builtin_amdgcn_mfma_f32_16x16x32_bf16(af[mi], bfr[ni], acc[2][mi][ni], 0, 0, 0);
      }
    }
    __syncthreads();
  }
  // epilogue: 3 outputs, all f16 (MFMA f16 path in attn)
  const int wm = w * 32;
  #pragma unroll
  for (int j = 0; j < 3; ++j) {
    const float* bias = (j == 0) ? bq : (j == 1) ? bk : bv;
    unsigned short* out = (j == 0) ? qo : (j == 1) ? ko : vo;
    #pragma unroll
    for (int mi = 0; mi < 2; ++mi) {
      #pragma unroll
      for (int ni = 0; ni < 2; ++ni) {
        const int col = bn * FBN + ni * 16 + r;
        const float bf = bias[col];
        #pragma unroll
        for (int i = 0; i < 4; ++i) {
          const int row = bm * FBM + wm + mi * 16 + quad * 4 + i;
          out[(size_t)row * C_DIM + col] = f2h(acc[j][mi][ni][i] + bf);
        }
      }
    }
  }
}

// ---- o-proj GEMM body: 64x64 tile, BK=128 (R6-verified) ----
__device__ __forceinline__ void gemm_body_64x64(
    const unsigned short* __restrict__ A, const unsigned short* __restrict__ W,
    f32x4 acc[2][2], int bm, int bn, int tid) {
  __shared__ unsigned short As[OBM * GBK];  // 16 KB
  __shared__ unsigned short Ws[OBN * GBK];  // 16 KB
  const int w = tid >> 6, lane = tid & 63;
  const int quad = lane >> 4, r = lane & 15;
  const int wm = (w >> 1) * 32, wn = (w & 1) * 32;
  const int sub = lane >> 4;
  const int c = lane & 15;
  const unsigned short* Arow[4];
  const unsigned short* Wrow[4];
  #pragma unroll
  for (int i = 0; i < 4; ++i) {
    const int row = w * 16 + i * 4 + sub;
    Arow[i] = A + (size_t)(bm * OBM + row) * C_DIM + ((c ^ (row & 7)) * 8);
    Wrow[i] = W + (size_t)(bn * OBN + row) * C_DIM + ((c ^ (row & 7)) * 8);
  }
  for (int kb = 0; kb < C_DIM; kb += GBK) {
    #pragma unroll
    for (int i = 0; i < 4; ++i)
      GLOAD_LDS16(Arow[i] + kb, &As[(w * 16 + i * 4) * GBK]);
    #pragma unroll
    for (int i = 0; i < 4; ++i)
      GLOAD_LDS16(Wrow[i] + kb, &Ws[(w * 16 + i * 4) * GBK]);
    __syncthreads();
    #pragma unroll
    for (int ks = 0; ks < 4; ++ks) {
      const int pc = ((ks * 4 + quad) ^ (r & 7)) * 8;
      short8 af[2], bfr[2];
      #pragma unroll
      for (int mi = 0; mi < 2; ++mi)
        af[mi] = *reinterpret_cast<const short8*>(&As[(wm + mi * 16 + r) * GBK + pc]);
      #pragma unroll
      for (int ni = 0; ni < 2; ++ni)
        bfr[ni] = *reinterpret_cast<const short8*>(&Ws[(wn + ni * 16 + r) * GBK + pc]);
      #pragma unroll
      for (int mi = 0; mi < 2; ++mi)
        #pragma unroll
        for (int ni = 0; ni < 2; ++ni)
          acc[mi][ni] = __builtin_amdgcn_mfma_f32_16x16x32_bf16(af[mi], bfr[ni], acc[mi][ni], 0, 0, 0);
    }
    __syncthreads();
  }
}

// ---- launch 5: output projection GEMM, fp32 out, 64x64 tile ----
__global__ __launch_bounds__(256) void gemm_o_f32_kernel(
    const unsigned short* __restrict__ A, const unsigned short* __restrict__ W,
    const float* __restrict__ bias, float* __restrict__ out) {
  const int tid = threadIdx.x;
  const int bm = blockIdx.x / (C_DIM / OBN);
  const int bn = blockIdx.x % (C_DIM / OBN);
  f32x4 acc[2][2] = {};
  gemm_body_64x64(A, W, acc, bm, bn, tid);
  const int w = tid >> 6, lane = tid & 63;
  const int quad = lane >> 4, r = lane & 15;
  const int wm = (w >> 1) * 32, wn = (w & 1) * 32;
  #pragma unroll
  for (int mi = 0; mi < 2; ++mi) {
    #pragma unroll
    for (int ni = 0; ni < 2; ++ni) {
      const int col = bn * OBN + wn + ni * 16 + r;
      const float bf = bias[col];
      #pragma unroll
      for (int i = 0; i < 4; ++i) {
        const int row = bm * OBM + wm + mi * 16 + quad * 4 + i;
        out[(size_t)row * C_DIM + col] = acc[mi][ni][i] + bf;
      }
    }
  }
}

// ---- launch 3: per-t top-64 selection (one wave per t, u16 row indices) ----
__global__ __launch_bounds__(256) void select_kernel(
    const int* __restrict__ sorted_idx, unsigned short* __restrict__ sel) {
  const int tid = threadIdx.x;
  const int w = tid >> 6, lane = tid & 63;
  const int t = blockIdx.x * 4 + w;
  unsigned short* dst = sel + (size_t)t * KSP;
  if (t <= 63) {
    // reference semantics: rows 0..t-1 once, row t duplicated (clamped -inf picks)
    dst[lane] = (unsigned short)((lane < t) ? lane : t);
    return;
  }
  const unsigned long long lt_mask = (1ull << lane) - 1ull;
  int count = 0;
  for (int c = 0; c < T_DIM / 64 && count < KSP; ++c) {
    int s = sorted_idx[c * 64 + lane];
    s = (s < 0) ? 0 : (s > T_DIM - 1 ? T_DIM - 1 : s);
    const bool ok = (s <= t);
    const unsigned long long mm = __ballot(ok);
    const int pos = count + __popcll(mm & lt_mask);
    if (ok && pos < KSP) dst[pos] = (unsigned short)s;
    count += __popcll(mm);
  }
}

// ---- launch 4: MFMA sparse attention, K direct-to-register (R9-verified).
// 32.4 KB arena -> 5 blocks/CU x 2 waves. ----
__global__ __launch_bounds__(128) void attn_kernel(
    const unsigned short* __restrict__ q, const unsigned short* __restrict__ k,
    const unsigned short* __restrict__ v, const unsigned short* __restrict__ sel,
    unsigned short* __restrict__ attn_out) {
  // arena carve:
  //   [0,26112)      Vt: 2 x 64 x 102 shorts
  //   [26112,32256)  Pl: 2 x 16 x 96 shorts; overlay map8[2048]+cnt8[1280]
  //   [32256,32416)  urows[80]
  __shared__ __align__(16) unsigned char arena[32416];
  unsigned short* VtB = reinterpret_cast<unsigned short*>(arena);
  unsigned short* PlB = reinterpret_cast<unsigned short*>(arena + 26112);
  unsigned char* map8 = arena + 26112;
  unsigned char* cnt8 = arena + 26112 + 2048;
  unsigned short* urows = reinterpret_cast<unsigned short*>(arena + 32256);
  const int tb = blockIdx.x >> 3;
  const int hg = blockIdx.x & 7;
  const int t0 = tb * ATB;
  const int tid = threadIdx.x;
  const int w = tid >> 6, lane = tid & 63;
  const int qd = lane >> 4;      // quad
  const int r = lane & 15;
  const int h = hg * 2 + w;
  unsigned short* Vtw = VtB + w * 64 * VTS;
  unsigned short* Plw = PlB + w * 16 * PLS;

  // hoist Q B-frags (global f16): lane (qd,r) holds Q[t0+r][kc*32+qd*8 ..+7]
  uint4 qf[2];
  #pragma unroll
  for (int kc = 0; kc < 2; ++kc)
    qf[kc] = *reinterpret_cast<const uint4*>(
        q + (size_t)(t0 + r) * C_DIM + h * HS + kc * 32 + qd * 8);

  // phase A: positional union (slots 0..78 + pad 79), map build (t0>=64),
  // cnt zero-init (t0>=64 path only; analytic path overwrites all entries)
  if (tid < KSP) {
    const int r0 = sel[(size_t)t0 * KSP + tid];
    urows[tid] = (unsigned short)r0;
    if (t0 >= 64) map8[r0] = (unsigned char)tid;  // rows distinct -> no race
  } else if (tid < 79) {
    const int row = t0 + 1 + (tid - KSP);
    urows[tid] = (unsigned short)row;
    if (t0 >= 64) map8[row] = (unsigned char)tid;
  } else if (tid == 79) {
    urows[79] = (unsigned short)t0;   // pad slot: real data, cnt=0 -> masked
  }
  if (t0 >= 64) {
    for (int i = tid; i < 320; i += 128)
      reinterpret_cast<unsigned*>(cnt8)[i] = 0u;
  }
  __syncthreads();

  // K A-frags direct from global: lane (qd,r) holds K[urows[ut*16+r]][kc*32+qd*8..+7]
  uint4 kf[5][2];
  #pragma unroll
  for (int ut = 0; ut < 5; ++ut) {
    const int rowg = urows[ut * 16 + r];
    const unsigned short* kr = k + (size_t)rowg * C_DIM + h * HS + qd * 8;
    kf[ut][0] = *reinterpret_cast<const uint4*>(kr);
    kf[ut][1] = *reinterpret_cast<const uint4*>(kr + 32);
  }

  // phase B: per-wave V gather/transpose + cooperative cnt build
  {
    const int e8 = lane & 7;
    const int pr = lane >> 3;  // row-pair id 0..7
    #pragma unroll
    for (int sb = 0; sb < 5; ++sb) {
      const int s0 = sb * 16 + pr * 2;
      const int row0 = urows[s0], row1 = urows[s0 + 1];
      const size_t g0 = (size_t)row0 * C_DIM + h * HS + e8 * 8;
      const size_t g1 = (size_t)row1 * C_DIM + h * HS + e8 * 8;
      const uint4 v0 = *reinterpret_cast<const uint4*>(v + g0);
      const uint4 v1 = *reinterpret_cast<const uint4*>(v + g1);
      const unsigned* v0w = reinterpret_cast<const unsigned*>(&v0);
      const unsigned* v1w = reinterpret_cast<const unsigned*>(&v1);
      // transpose-scatter: Vt[d][s0..s0+1] as one u32 (pair-packed)
      #pragma unroll
      for (int dd = 0; dd < 8; ++dd) {
        const unsigned lo = (v0w[dd >> 1] >> ((dd & 1) * 16)) & 0xffffu;
        const unsigned hi = (v1w[dd >> 1] >> ((dd & 1) * 16)) & 0xffffu;
        *reinterpret_cast<unsigned*>(&Vtw[(e8 * 8 + dd) * VTS + s0]) =
            lo | (hi << 16);
      }
    }
    // zero Vt pad cols u=80..95
    #pragma unroll
    for (int z = 0; z < 8; ++z)
      *reinterpret_cast<unsigned*>(&Vtw[lane * VTS + 80 + z * 2]) = 0u;
    // cnt build (shared by both waves, cooperative)
    if (t0 >= 64) {
      #pragma unroll
      for (int e = 0; e < 8; ++e) {
        const int idx = tid + e * 128;
        const int tl = idx >> 6;
        const int rr = sel[(size_t)(t0 + tl) * KSP + (idx & 63)];
        cnt8[tl * 80 + map8[rr]] = 1;  // distinct rows per t -> no race
      }
    } else if (tid < 80) {
      // analytic multiplicities for t<64: sel(t) = rows 0..t-1 once +
      // row t x(64-t). Deterministic dup slot = t0.
      const int s = tid;
      #pragma unroll
      for (int tl = 0; tl < ATB; ++tl) {
        const int t = t0 + tl;
        int c;
        if (s < t0)        c = 1;
        else if (s == t0)  c = (tl == 0) ? (64 - t) : 1;
        else if (s < 64)   c = 0;                     // unused dup slots
        else if (s < 79) {
          const int row = t0 + 1 + (s - 64);
          c = (row < t) ? 1 : ((row == t) ? (64 - t) : 0);
        } else c = 0;                                 // pad slot
        cnt8[tl * 80 + s] = (unsigned char)c;
      }
    }
  }
  __syncthreads();

  // S^T = K @ Q^T; lane holds S[u=ut*16+qd*4+i][t=r]
  f32x4 s5[5] = {};
  #pragma unroll
  for (int ut = 0; ut < 5; ++ut) {
    #pragma unroll
    for (int kc = 0; kc < 2; ++kc) {
      s5[ut] = __builtin_amdgcn_mfma_f32_16x16x32_f16(
          __builtin_bit_cast(half8, kf[ut][kc]), __builtin_bit_cast(half8, qf[kc]),
          s5[ut], 0, 0, 0);
    }
  }
  // bias (mask/multiplicity) + row-max
  float mx = -3.0e38f;
  #pragma unroll
  for (int ut = 0; ut < 5; ++ut) {
    const unsigned c4 =
        *reinterpret_cast<const unsigned*>(cnt8 + r * 80 + ut * 16 + qd * 4);
    #pragma unroll
    for (int i = 0; i < 4; ++i) {
      const unsigned cc = (c4 >> (8 * i)) & 0xffu;
      float lg = s5[ut][i] * 0.125f;
      lg = (cc == 0u) ? -3.0e38f
         : (cc == 1u) ? lg : (lg + __logf((float)cc));
      s5[ut][i] = lg;
      mx = fmaxf(mx, lg);
    }
  }
  mx = fmaxf(mx, __shfl_xor(mx, 16));
  mx = fmaxf(mx, __shfl_xor(mx, 32));
  float sum = 0.f;
  #pragma unroll
  for (int ut = 0; ut < 5; ++ut)
    #pragma unroll
    for (int i = 0; i < 4; ++i) {
      const float e = __expf(s5[ut][i] - mx);
      s5[ut][i] = e;
      sum += e;
    }
  sum += __shfl_xor(sum, 16);
  sum += __shfl_xor(sum, 32);
  const float rs = 1.0f / sum;
  // barrier: cnt8/map8 (overlaid on Pl) must be fully read by BOTH waves
  // before any Pl write
  __syncthreads();
  // P -> f16 into Pl[t][u] (wave-local roundtrip)
  #pragma unroll
  for (int ut = 0; ut < 5; ++ut) {
    const unsigned w0 = (unsigned)f2h(s5[ut][0] * rs) |
                        ((unsigned)f2h(s5[ut][1] * rs) << 16);
    const unsigned w1 = (unsigned)f2h(s5[ut][2] * rs) |
                        ((unsigned)f2h(s5[ut][3] * rs) << 16);
    unsigned* p32 = reinterpret_cast<unsigned*>(&Plw[r * PLS + ut * 16 + qd * 4]);
    p32[0] = w0;
    p32[1] = w1;
  }
  // zero Pl pad u=80..95 (4 shorts per quad)
  *reinterpret_cast<unsigned long long*>(&Plw[r * PLS + 80 + qd * 4]) = 0ull;
  // PV: O^T[d][t] = Vt @ P; A = Vt rows (d), B = Pl cols (t)
  f32x4 o4[4] = {};
  #pragma unroll
  for (int c = 0; c < 3; ++c) {
    const uint4 pw = *reinterpret_cast<const uint4*>(&Plw[r * PLS + c * 32 + qd * 8]);
    #pragma unroll
    for (int mt = 0; mt < 4; ++mt) {
      const unsigned short* vb_ = &Vtw[(mt * 16 + r) * VTS + c * 32 + qd * 8];
      uint4 vw;
      vw.x = *reinterpret_cast<const unsigned*>(vb_);
      vw.y = *reinterpret_cast<const unsigned*>(vb_ + 2);
      vw.z = *reinterpret_cast<const unsigned*>(vb_ + 4);
      vw.w = *reinterpret_cast<const unsigned*>(vb_ + 6);
      o4[mt] = __builtin_amdgcn_mfma_f32_16x16x32_f16(
          __builtin_bit_cast(half8, vw), __builtin_bit_cast(half8, pw),
          o4[mt], 0, 0, 0);
    }
  }
  // store: lane holds O[t=r][d = mt*16 + qd*4 + i], bf16 out
  #pragma unroll
  for (int mt = 0; mt < 4; ++mt) {
    ushort4 ov;
    ov.x = f2bfu(o4[mt][0]); ov.y = f2bfu(o4[mt][1]);
    ov.z = f2bfu(o4[mt][2]); ov.w = f2bfu(o4[mt][3]);
    *reinterpret_cast<ushort4*>(
        attn_out + (size_t)(t0 + r) * C_DIM + h * HS + mt * 16 + qd * 4) = ov;
  }
}

extern "C" void kernel_launch(void* const* d_in, const int* in_sizes, int n_in,
                              void* d_out, int out_size, void* d_ws, size_t ws_size,
                              hipStream_t stream) {
  const float* x   = (const float*)d_in[0];
  const float* Wq  = (const float*)d_in[1];
  const float* bq  = (const float*)d_in[2];
  const float* Wk  = (const float*)d_in[3];
  const float* bk  = (const float*)d_in[4];
  const float* Wv  = (const float*)d_in[5];
  const float* bv  = (const float*)d_in[6];
  const float* Wo  = (const float*)d_in[7];
  const float* bo  = (const float*)d_in[8];
  const float* Wks = (const float*)d_in[9];
  const float* bks = (const float*)d_in[10];
  float* out = (float*)d_out;

  char* ws = (char*)d_ws;
  size_t off = 0;
  float* scores = (float*)(ws + off); off += 8192;
  int*   sorted = (int*)(ws + off);   off += 8192;
  unsigned short* selb = (unsigned short*)(ws + off); off += (size_t)T_DIM * KSP * 2;
  unsigned short* xb  = (unsigned short*)(ws + off); off += (size_t)T_DIM * C_DIM * 2;
  unsigned short* Wqb = (unsigned short*)(ws + off); off += (size_t)C_DIM * C_DIM * 2;
  unsigned short* Wkb = (unsigned short*)(ws + off); off += (size_t)C_DIM * C_DIM * 2;
  unsigned short* Wvb = (unsigned short*)(ws + off); off += (size_t)C_DIM * C_DIM * 2;
  unsigned short* Wob = (unsigned short*)(ws + off); off += (size_t)C_DIM * C_DIM * 2;
  unsigned short* qb  = (unsigned short*)(ws + off); off += (size_t)T_DIM * C_DIM * 2;
  unsigned short* kb  = (unsigned short*)(ws + off); off += (size_t)T_DIM * C_DIM * 2;
  unsigned short* vb  = (unsigned short*)(ws + off); off += (size_t)T_DIM * C_DIM * 2;
  unsigned short* ab  = xb;  // alias: xb dead after gemm_qkv

  // launch 1: conversion + scores
  convert_scores_kernel<<<NSCORE + NCONV, 256, 0, stream>>>(
      x, Wq, Wk, Wv, Wo, Wks, bks, xb, Wqb, Wkb, Wvb, Wob, scores);

  // launch 2: rank-sort (512 blocks) + fused QKV GEMM (512 blocks)
  gemm_qkv_rank_kernel<<<NRANK + FPER, 256, 0, stream>>>(
      xb, Wqb, Wkb, Wvb, bq, bk, bv, qb, kb, vb, scores, sorted);

  // launch 3: per-t top-64 selection (one wave per t)
  select_kernel<<<T_DIM / 4, 256, 0, stream>>>(sorted, selb);

  // launch 4: MFMA attention (128 t-tiles x 8 head-pairs = 1024 blocks)
  attn_kernel<<<(T_DIM / ATB) * (NH / 2), 128, 0, stream>>>(qb, kb, vb, selb, ab);

  // launch 5: output projection (512 blocks, 64x64)
  gemm_o_f32_kernel<<<(T_DIM / OBM) * (C_DIM / OBN), 256, 0, stream>>>(
      ab, Wob, bo, out);
}